// Round 6
// baseline (175.868 us; speedup 1.0000x reference)
//
#include <hip/hip_runtime.h>
#include <stdint.h>

#define NH     16
#define LSEQ   2048
#define DH     64
#define HDIM   1024
#define BATCH  2

typedef __attribute__((ext_vector_type(8))) short bf16x8;
typedef __attribute__((ext_vector_type(8))) unsigned short u16x8;
typedef __attribute__((ext_vector_type(4))) float f32x4;

// fp32 -> bf16 (RNE)
static __device__ inline unsigned short f2bs(float f) {
    union { float f; uint32_t u; } v; v.f = f;
    uint32_t u = v.u;
    return (unsigned short)((u + 0x7FFFu + ((u >> 16) & 1u)) >> 16);
}
static __device__ inline float bf2f(unsigned short s) {
    return __uint_as_float(((uint32_t)s) << 16);
}

#define GLOAD_LDS(gp, lp) \
    __builtin_amdgcn_global_load_lds((const __attribute__((address_space(1))) void*)(gp), \
                                     (__attribute__((address_space(3))) void*)(lp), 16, 0, 0)

// sqrt(0.125 * log2(e)) — folded into xb so (sQ)·(sK) carries the full softmax scale
#define QK_SCALE 0.42466083f

// ---------------------------------------------------------------------------
// Kernel 1: W fp32 -> bf16 (plain row-major)
// ---------------------------------------------------------------------------
__global__ __launch_bounds__(256) void cvt_kernel(const float* __restrict__ W,
                                                  unsigned short* __restrict__ Wb,
                                                  int n) {
    int i = (blockIdx.x * 256 + threadIdx.x) * 4;
    if (i < n) {
        float4 f = *(const float4*)(W + i);
        *(ushort4*)(Wb + i) = make_ushort4(f2bs(f.x), f2bs(f.y), f2bs(f.z), f2bs(f.w));
    }
}

// ---------------------------------------------------------------------------
// Kernel 2: x fp32 [B][L][H] -> bf16 head-major tiles.
//   xb: K/Q tiles [b][h][lt][64 kv x 64 d], PLAIN layout, scaled by QK_SCALE
//   xt: V^T tiles [b][h][lt][64 d x 64 kv], XOR-swizzled (chunk c at c^(d&7))
// grid (32 lt, 32 bh), 256 threads.
// ---------------------------------------------------------------------------
__global__ __launch_bounds__(256) void xcvt_kernel(const float* __restrict__ x,
                                                   unsigned short* __restrict__ xb,
                                                   unsigned short* __restrict__ xt) {
    const int lt = blockIdx.x, bh = blockIdx.y;
    const int b = bh >> 4, h = bh & 15;
    const int t = threadIdx.x;
    const int r = t >> 2, cp = t & 3;          // row 0..63, 16-d chunk-pair 0..3

    __shared__ __align__(16) unsigned short Sm[64][80];

    const float* src = x + ((size_t)(b * LSEQ + lt * 64 + r)) * HDIM + h * DH + cp * 16;
    float4 f0 = *(const float4*)(src);
    float4 f1 = *(const float4*)(src + 4);
    float4 f2 = *(const float4*)(src + 8);
    float4 f3 = *(const float4*)(src + 12);
    // unscaled (for V)
    u16x8 lo, hi;
    lo[0]=f2bs(f0.x); lo[1]=f2bs(f0.y); lo[2]=f2bs(f0.z); lo[3]=f2bs(f0.w);
    lo[4]=f2bs(f1.x); lo[5]=f2bs(f1.y); lo[6]=f2bs(f1.z); lo[7]=f2bs(f1.w);
    hi[0]=f2bs(f2.x); hi[1]=f2bs(f2.y); hi[2]=f2bs(f2.z); hi[3]=f2bs(f2.w);
    hi[4]=f2bs(f3.x); hi[5]=f2bs(f3.y); hi[6]=f2bs(f3.z); hi[7]=f2bs(f3.w);
    // scaled (for Q/K)
    u16x8 slo, shi;
    slo[0]=f2bs(f0.x*QK_SCALE); slo[1]=f2bs(f0.y*QK_SCALE); slo[2]=f2bs(f0.z*QK_SCALE); slo[3]=f2bs(f0.w*QK_SCALE);
    slo[4]=f2bs(f1.x*QK_SCALE); slo[5]=f2bs(f1.y*QK_SCALE); slo[6]=f2bs(f1.z*QK_SCALE); slo[7]=f2bs(f1.w*QK_SCALE);
    shi[0]=f2bs(f2.x*QK_SCALE); shi[1]=f2bs(f2.y*QK_SCALE); shi[2]=f2bs(f2.z*QK_SCALE); shi[3]=f2bs(f2.w*QK_SCALE);
    shi[4]=f2bs(f3.x*QK_SCALE); shi[5]=f2bs(f3.y*QK_SCALE); shi[6]=f2bs(f3.z*QK_SCALE); shi[7]=f2bs(f3.w*QK_SCALE);

    unsigned short* kt = xb + ((size_t)(bh * 32 + lt)) * 4096;
    *(u16x8*)(kt + r * 64 + cp * 16)     = slo;   // plain layout
    *(u16x8*)(kt + r * 64 + cp * 16 + 8) = shi;
    *(u16x8*)&Sm[r][cp * 16]     = lo;
    *(u16x8*)&Sm[r][cp * 16 + 8] = hi;
    __syncthreads();

    // transpose: thread -> row d, two 8-kv chunks (XOR swizzle)
    const int d = t >> 2, kq = t & 3;
    unsigned short* vt = xt + ((size_t)(bh * 32 + lt)) * 4096;
    u16x8 g0, g1;
    #pragma unroll
    for (int j = 0; j < 8; ++j) {
        g0[j] = Sm[(2*kq)   * 8 + j][d];
        g1[j] = Sm[(2*kq+1) * 8 + j][d];
    }
    *(u16x8*)(vt + d * 64 + (((2*kq)   ^ (d & 7)) * 8)) = g0;
    *(u16x8*)(vt + d * 64 + (((2*kq+1) ^ (d & 7)) * 8)) = g1;
}

// ---------------------------------------------------------------------------
// Kernel 3: flash attention, KV-split x2. grid (32 bh, 16 qt, 2 ks);
// block 256 = 4 waves, wave owns 32 q, each block does 16 KV tiles (1024 kv).
// K frags software-pipelined in VGPRs (loaded 1 iter ahead, WAR on MFMA issue);
// V double-buffered LDS via global_load_lds; ONE barrier/iter.
// Row-sums l computed by MFMA against a constant all-ones B fragment.
// ---------------------------------------------------------------------------
__global__ __launch_bounds__(256, 4) void attn_kernel(const unsigned short* __restrict__ xb,
                                                      const unsigned short* __restrict__ xt,
                                                      unsigned short* __restrict__ po,
                                                      float* __restrict__ pl) {
    const int bh = blockIdx.x;
    const int qt = blockIdx.y;
    const int ks = blockIdx.z;
    const int tid = threadIdx.x;
    const int w = tid >> 6, lane = tid & 63;
    const int la = lane & 15, quad = lane >> 4;

    __shared__ __align__(16) unsigned short Vt[2][4096];
    __shared__ __align__(16) unsigned short Pt[4][32][88];

    const unsigned short* xbh = xb + (size_t)bh * 32 * 4096;
    const unsigned short* xth = xt + (size_t)bh * 32 * 4096;
    const int qbase = qt * 128 + w * 32;
    const int t0 = ks * 16;

    // XOR-swizzle offsets (Vt reads only)
    const int sw0 = ((quad)     ^ (la & 7)) * 8;
    const int sw1 = ((quad + 4) ^ (la & 7)) * 8;

    // Q B-frags (plain layout, pre-scaled)
    bf16x8 qf[2][2];
    #pragma unroll
    for (int qnt = 0; qnt < 2; ++qnt) {
        const int q = qbase + qnt * 16 + la;
        const unsigned short* qs = xbh + (q >> 6) * 4096 + (q & 63) * 64;
        qf[qnt][0] = *(const bf16x8*)(qs + quad * 8);
        qf[qnt][1] = *(const bf16x8*)(qs + 32 + quad * 8);
    }

    // constant all-ones B fragment (bf16 1.0 = 0x3F80) for row-sum MFMA
    bf16x8 onesf;
    #pragma unroll
    for (int j = 0; j < 8; ++j) onesf[j] = (short)0x3F80;

    const f32x4 fzero = {0.f, 0.f, 0.f, 0.f};
    f32x4 acc[2][4];
    #pragma unroll
    for (int i = 0; i < 2; ++i)
        #pragma unroll
        for (int j = 0; j < 4; ++j) acc[i][j] = fzero;
    f32x4 accl[2] = {fzero, fzero};

    // prologue: K frags for tile t0 into VGPRs
    bf16x8 kf[4][2];
    {
        const unsigned short* ktile = xbh + t0 * 4096;
        #pragma unroll
        for (int kvt = 0; kvt < 4; ++kvt) {
            const unsigned short* krow = ktile + kvt * 1024 + la * 64;
            kf[kvt][0] = *(const bf16x8*)(krow + quad * 8);
            kf[kvt][1] = *(const bf16x8*)(krow + 32 + quad * 8);
        }
    }
    // prologue: stage V tile t0 into buffer 0
    {
        const char* vsrc = (const char*)(xth + t0 * 4096);
        char* vdst = (char*)Vt[0];
        #pragma unroll
        for (int j = 0; j < 2; ++j) {
            const int off = (j * 256 + tid) * 16;
            GLOAD_LDS(vsrc + off, vdst + off);
        }
    }

    for (int tt = 0; tt < 16; ++tt) {
        const int t = t0 + tt;

        // --- S^T = K Q^T from register-resident kf ---
        f32x4 st[4][2];
        #pragma unroll
        for (int kvt = 0; kvt < 4; ++kvt) {
            #pragma unroll
            for (int qnt = 0; qnt < 2; ++qnt) {
                f32x4 s = fzero;
                s = __builtin_amdgcn_mfma_f32_16x16x32_bf16(kf[kvt][0], qf[qnt][0], s, 0, 0, 0);
                s = __builtin_amdgcn_mfma_f32_16x16x32_bf16(kf[kvt][1], qf[qnt][1], s, 0, 0, 0);
                st[kvt][qnt] = s;
            }
        }

        // --- prefetch K frags for tile t+1 (used after next barrier; WAR ok) ---
        if (tt < 15) {
            const unsigned short* ktile = xbh + (t + 1) * 4096;
            #pragma unroll
            for (int kvt = 0; kvt < 4; ++kvt) {
                const unsigned short* krow = ktile + kvt * 1024 + la * 64;
                kf[kvt][0] = *(const bf16x8*)(krow + quad * 8);
                kf[kvt][1] = *(const bf16x8*)(krow + 32 + quad * 8);
            }
        }

        // --- raw v_exp_f32 (scale pre-folded), pack, write P[q][kv] ---
        #pragma unroll
        for (int qnt = 0; qnt < 2; ++qnt) {
            #pragma unroll
            for (int kvt = 0; kvt < 4; ++kvt) {
                float p0 = __builtin_amdgcn_exp2f(st[kvt][qnt][0]);
                float p1 = __builtin_amdgcn_exp2f(st[kvt][qnt][1]);
                float p2 = __builtin_amdgcn_exp2f(st[kvt][qnt][2]);
                float p3 = __builtin_amdgcn_exp2f(st[kvt][qnt][3]);
                uint32_t u0 = __float_as_uint(p0) + 0x8000u;
                uint32_t u1 = __float_as_uint(p1) + 0x8000u;
                uint32_t u2 = __float_as_uint(p2) + 0x8000u;
                uint32_t u3 = __float_as_uint(p3) + 0x8000u;
                uint32_t w0 = __builtin_amdgcn_perm(u1, u0, 0x07060302);
                uint32_t w1 = __builtin_amdgcn_perm(u3, u2, 0x07060302);
                *(uint2*)&Pt[w][qnt * 16 + la][kvt * 16 + quad * 4] = make_uint2(w0, w1);
            }
        }

        __syncthreads();   // P writes visible; V stage (issued last iter) drained

        // stage V tile t+1 into the other buffer (hidden behind next iteration)
        if (tt < 15) {
            const char* vsrc = (const char*)(xth + (t + 1) * 4096);
            char* vdst = (char*)Vt[(tt + 1) & 1];
            #pragma unroll
            for (int j = 0; j < 2; ++j) {
                const int off = (j * 256 + tid) * 16;
                GLOAD_LDS(vsrc + off, vdst + off);
            }
        }

        // --- O += P V ; l += P·1 ---
        const unsigned short* vb = Vt[tt & 1];
        bf16x8 pf[2][2];
        #pragma unroll
        for (int qnt = 0; qnt < 2; ++qnt) {
            pf[qnt][0] = *(const bf16x8*)&Pt[w][qnt * 16 + la][quad * 8];
            pf[qnt][1] = *(const bf16x8*)&Pt[w][qnt * 16 + la][32 + quad * 8];
        }
        #pragma unroll
        for (int dt = 0; dt < 4; ++dt) {
            const unsigned short* vrow = vb + dt * 1024 + la * 64;
            bf16x8 vf0 = *(const bf16x8*)(vrow + sw0);
            bf16x8 vf1 = *(const bf16x8*)(vrow + sw1);
            #pragma unroll
            for (int qnt = 0; qnt < 2; ++qnt) {
                f32x4 a = acc[qnt][dt];
                a = __builtin_amdgcn_mfma_f32_16x16x32_bf16(pf[qnt][0], vf0, a, 0, 0, 0);
                a = __builtin_amdgcn_mfma_f32_16x16x32_bf16(pf[qnt][1], vf1, a, 0, 0, 0);
                acc[qnt][dt] = a;
            }
        }
        #pragma unroll
        for (int qnt = 0; qnt < 2; ++qnt) {
            f32x4 a = accl[qnt];
            a = __builtin_amdgcn_mfma_f32_16x16x32_bf16(pf[qnt][0], onesf, a, 0, 0, 0);
            a = __builtin_amdgcn_mfma_f32_16x16x32_bf16(pf[qnt][1], onesf, a, 0, 0, 0);
            accl[qnt] = a;
        }
    }

    // --- epilogue: unnormalized partial O (bf16) + partial l (fp32) ---
    // accl[qnt][r] = l(q = qnt*16 + quad*4 + r), identical across la.
    const size_t prow = (size_t)(ks * 32 + bh) * 2048 + qbase;
    unsigned short* pob = po + prow * 64;
    #pragma unroll
    for (int qnt = 0; qnt < 2; ++qnt) {
        #pragma unroll
        for (int r = 0; r < 4; ++r) {
            unsigned short* orow = pob + (size_t)(qnt * 16 + quad * 4 + r) * 64 + la;
            #pragma unroll
            for (int dt = 0; dt < 4; ++dt)
                orow[dt * 16] = f2bs(acc[qnt][dt][r]);
        }
    }
    if (la == 0) {
        #pragma unroll
        for (int qnt = 0; qnt < 2; ++qnt)
            #pragma unroll
            for (int r = 0; r < 4; ++r)
                pl[prow + qnt * 16 + quad * 4 + r] = accl[qnt][r];
    }
}

// ---------------------------------------------------------------------------
// Kernel 4: combine 2 KV-splits: ctx = (O1+O2)/(l1+l2), bf16 out.
// grid 4096 x 256 threads; each thread does 4 d's of one row.
// ---------------------------------------------------------------------------
__global__ __launch_bounds__(256) void reduce_kernel(const unsigned short* __restrict__ po,
                                                     const float* __restrict__ pl,
                                                     unsigned short* __restrict__ ctx) {
    const int gid = blockIdx.x * 256 + threadIdx.x;   // 0 .. 1,048,575
    const int rid = gid >> 4;                          // row 0..65535 (bh*2048+q)
    const int d0  = (gid & 15) * 4;
    const float invl = 1.0f / (pl[rid] + pl[65536 + rid]);
    ushort4 a = *(const ushort4*)(po + (size_t)rid * 64 + d0);
    ushort4 c = *(const ushort4*)(po + (size_t)65536 * 64 + (size_t)rid * 64 + d0);
    const int bh = rid >> 11, q = rid & 2047;
    const int b = bh >> 4, h = bh & 15;
    unsigned short* dst = ctx + (((size_t)(b * 2048 + q) * 16 + h) * 64) + d0;
    *(ushort4*)dst = make_ushort4(
        f2bs((bf2f(a.x) + bf2f(c.x)) * invl),
        f2bs((bf2f(a.y) + bf2f(c.y)) * invl),
        f2bs((bf2f(a.z) + bf2f(c.z)) * invl),
        f2bs((bf2f(a.w) + bf2f(c.w)) * invl));
}

// ---------------------------------------------------------------------------
// Kernel 5: out = ctx @ W^T + b (gemm_bt, bf16 MFMA, fp32 out).
// Tiles 128m x 64n -> grid (16, 32) = 512 blocks (2/CU). Block 256 = 4 waves,
// wave quadrant 64m x 32n.
// ---------------------------------------------------------------------------
__global__ __launch_bounds__(256) void proj_kernel(const unsigned short* __restrict__ A,
                                                   const unsigned short* __restrict__ Bw,
                                                   const float* __restrict__ bias,
                                                   float* __restrict__ out) {
    const int n0 = blockIdx.x * 64;
    const int m0 = blockIdx.y * 128;
    const int tid = threadIdx.x;
    const int w = tid >> 6, lane = tid & 63;
    const int la = lane & 15, quad = lane >> 4;
    const int wm = (w >> 1) * 64, wn = (w & 1) * 32;
    const int K = HDIM;

    __shared__ __align__(16) unsigned short As[128 * 32];
    __shared__ __align__(16) unsigned short Bs[64 * 32];

    const f32x4 fzero = {0.f, 0.f, 0.f, 0.f};
    f32x4 acc[4][2];
    #pragma unroll
    for (int i = 0; i < 4; ++i)
        #pragma unroll
        for (int j = 0; j < 2; ++j) acc[i][j] = fzero;

    for (int k0 = 0; k0 < K; k0 += 32) {
        __syncthreads();
        #pragma unroll
        for (int j = 0; j < 2; ++j) {
            const int fc = j * 256 + tid;          // A: 16B chunk id, 0..511
            GLOAD_LDS(A + (size_t)(m0 + (fc >> 2)) * K + k0 + (fc & 3) * 8, (char*)As + fc * 16);
        }
        GLOAD_LDS(Bw + (size_t)(n0 + (tid >> 2)) * K + k0 + (tid & 3) * 8, (char*)Bs + tid * 16);
        __syncthreads();

        bf16x8 af[4], bfr[2];
        #pragma unroll
        for (int mt = 0; mt < 4; ++mt) af[mt]  = *(const bf16x8*)&As[(wm + mt * 16 + la) * 32 + quad * 8];
        #pragma unroll
        for (int nt = 0; nt < 2; ++nt) bfr[nt] = *(const bf16x8*)&Bs[(wn + nt * 16 + la) * 32 + quad * 8];
        #pragma unroll
        for (int mt = 0; mt < 4; ++mt)
            #pragma unroll
            for (int nt = 0; nt < 2; ++nt)
                acc[mt][nt] = __builtin_amdgcn_mfma_f32_16x16x32_bf16(af[mt], bfr[nt], acc[mt][nt], 0, 0, 0);
    }

    #pragma unroll
    for (int nt = 0; nt < 2; ++nt) {
        const int n = n0 + wn + nt * 16 + la;
        const float bv = bias[n];
        #pragma unroll
        for (int mt = 0; mt < 4; ++mt)
            #pragma unroll
            for (int r = 0; r < 4; ++r) {
                const int m = m0 + wm + mt * 16 + quad * 4 + r;
                out[(size_t)m * HDIM + n] = acc[mt][nt][r] + bv;
            }
    }
}

// ---------------------------------------------------------------------------
extern "C" void kernel_launch(void* const* d_in, const int* in_sizes, int n_in,
                              void* d_out, int out_size, void* d_ws, size_t ws_size,
                              hipStream_t stream) {
    const float* x    = (const float*)d_in[0];
    const float* W    = (const float*)d_in[1];
    const float* bias = (const float*)d_in[2];
    float* out = (float*)d_out;

    // ws (bytes): ctx 8M | xb 8M | xt 8M | Wb 2M | po 16M | pl 0.5M  = 42.5M
    unsigned short* ctx = (unsigned short*)d_ws;
    unsigned short* xbp = (unsigned short*)((char*)d_ws + ( 8u << 20));
    unsigned short* xtp = (unsigned short*)((char*)d_ws + (16u << 20));
    unsigned short* Wb  = (unsigned short*)((char*)d_ws + (24u << 20));
    unsigned short* po  = (unsigned short*)((char*)d_ws + (26u << 20));
    float*          pl  = (float*)         ((char*)d_ws + (42u << 20));

    cvt_kernel<<<dim3(HDIM * HDIM / 1024), 256, 0, stream>>>(W, Wb, HDIM * HDIM);
    xcvt_kernel<<<dim3(32, 32), 256, 0, stream>>>(x, xbp, xtp);
    attn_kernel<<<dim3(32, 16, 2), 256, 0, stream>>>(xbp, xtp, po, pl);
    reduce_kernel<<<dim3(4096), 256, 0, stream>>>(po, pl, ctx);
    proj_kernel<<<dim3(16, 32), 256, 0, stream>>>(ctx, Wb, bias, out);
}

// Round 7
// 157.415 us; speedup vs baseline: 1.1172x; 1.1172x over previous
//
#include <hip/hip_runtime.h>
#include <stdint.h>

#define NH     16
#define LSEQ   2048
#define DH     64
#define HDIM   1024
#define BATCH  2

typedef __attribute__((ext_vector_type(8))) short bf16x8;
typedef __attribute__((ext_vector_type(4))) short bf16x4;
typedef __attribute__((ext_vector_type(8))) unsigned short u16x8;
typedef __attribute__((ext_vector_type(4))) float f32x4;

// fp32 -> bf16 (RNE)
static __device__ inline unsigned short f2bs(float f) {
    union { float f; uint32_t u; } v; v.f = f;
    uint32_t u = v.u;
    return (unsigned short)((u + 0x7FFFu + ((u >> 16) & 1u)) >> 16);
}
static __device__ inline float bf2f(unsigned short s) {
    return __uint_as_float(((uint32_t)s) << 16);
}

#define GLOAD_LDS(gp, lp) \
    __builtin_amdgcn_global_load_lds((const __attribute__((address_space(1))) void*)(gp), \
                                     (__attribute__((address_space(3))) void*)(lp), 16, 0, 0)

// sqrt(0.125 * log2(e)) — folded into xb so (sQ)·(sK) carries the softmax scale
#define QK_SCALE 0.42466083f

// ---------------------------------------------------------------------------
// Kernel 1: W fp32 -> bf16 (plain row-major)
// ---------------------------------------------------------------------------
__global__ __launch_bounds__(256) void cvt_kernel(const float* __restrict__ W,
                                                  unsigned short* __restrict__ Wb,
                                                  int n) {
    int i = (blockIdx.x * 256 + threadIdx.x) * 4;
    if (i < n) {
        float4 f = *(const float4*)(W + i);
        *(ushort4*)(Wb + i) = make_ushort4(f2bs(f.x), f2bs(f.y), f2bs(f.z), f2bs(f.w));
    }
}

// ---------------------------------------------------------------------------
// Kernel 2: x fp32 [B][L][H] -> bf16 FRAGMENT-MAJOR head tiles.
//  xb (scaled, Q/K): per 64-row tile, frag (s=row>>4, ks) chunk for lane:
//     offset ((s*2+ks)*64 + lane)*8 shorts = Ks[s*16 + (lane&15)][ks*32+(lane>>4)*8 + j]
//  xt (unscaled, V): per tile, chunk (dt, lane) of 16 shorts [kvt][j]:
//     offset (dt*64+lane)*16 shorts = V^T[dt*16+(lane&15)][kvt*16+(lane>>4)*4 + j]
// grid (32 lt, 32 bh), 256 threads.
// ---------------------------------------------------------------------------
__global__ __launch_bounds__(256) void xcvt_kernel(const float* __restrict__ x,
                                                   unsigned short* __restrict__ xb,
                                                   unsigned short* __restrict__ xt) {
    const int lt = blockIdx.x, bh = blockIdx.y;
    const int b = bh >> 4, h = bh & 15;
    const int t = threadIdx.x;
    const int r = t >> 2, cp = t & 3;          // row 0..63, 16-d chunk-pair 0..3

    __shared__ __align__(16) unsigned short Sm[64][72];   // unscaled tile

    const float* src = x + ((size_t)(b * LSEQ + lt * 64 + r)) * HDIM + h * DH + cp * 16;
    float4 f0 = *(const float4*)(src);
    float4 f1 = *(const float4*)(src + 4);
    float4 f2 = *(const float4*)(src + 8);
    float4 f3 = *(const float4*)(src + 12);
    // unscaled (for V)
    u16x8 lo, hi;
    lo[0]=f2bs(f0.x); lo[1]=f2bs(f0.y); lo[2]=f2bs(f0.z); lo[3]=f2bs(f0.w);
    lo[4]=f2bs(f1.x); lo[5]=f2bs(f1.y); lo[6]=f2bs(f1.z); lo[7]=f2bs(f1.w);
    hi[0]=f2bs(f2.x); hi[1]=f2bs(f2.y); hi[2]=f2bs(f2.z); hi[3]=f2bs(f2.w);
    hi[4]=f2bs(f3.x); hi[5]=f2bs(f3.y); hi[6]=f2bs(f3.z); hi[7]=f2bs(f3.w);
    // scaled (for Q/K)
    u16x8 slo, shi;
    slo[0]=f2bs(f0.x*QK_SCALE); slo[1]=f2bs(f0.y*QK_SCALE); slo[2]=f2bs(f0.z*QK_SCALE); slo[3]=f2bs(f0.w*QK_SCALE);
    slo[4]=f2bs(f1.x*QK_SCALE); slo[5]=f2bs(f1.y*QK_SCALE); slo[6]=f2bs(f1.z*QK_SCALE); slo[7]=f2bs(f1.w*QK_SCALE);
    shi[0]=f2bs(f2.x*QK_SCALE); shi[1]=f2bs(f2.y*QK_SCALE); shi[2]=f2bs(f2.z*QK_SCALE); shi[3]=f2bs(f2.w*QK_SCALE);
    shi[4]=f2bs(f3.x*QK_SCALE); shi[5]=f2bs(f3.y*QK_SCALE); shi[6]=f2bs(f3.z*QK_SCALE); shi[7]=f2bs(f3.w*QK_SCALE);

    // xb frag-major direct write: this thread covers (s, ks) with quads q0=(cp&1)*2, q0+1
    {
        unsigned short* kt = xb + ((size_t)(bh * 32 + lt)) * 4096;
        const int s  = r >> 4, la = r & 15;
        const int ks = cp >> 1, q0 = (cp & 1) * 2;
        *(u16x8*)(kt + ((s * 2 + ks) * 64 + q0 * 16 + la) * 8)       = slo;
        *(u16x8*)(kt + ((s * 2 + ks) * 64 + (q0 + 1) * 16 + la) * 8) = shi;
    }
    *(u16x8*)&Sm[r][cp * 16]     = lo;
    *(u16x8*)&Sm[r][cp * 16 + 8] = hi;
    __syncthreads();

    // V frag-packed gather: thread -> one 16-short chunk (dt, lane)
    {
        const int dt = t >> 6, lane = t & 63;
        const int la = lane & 15, quad = lane >> 4;
        u16x8 g0, g1;
        #pragma unroll
        for (int kvt = 0; kvt < 2; ++kvt)
            #pragma unroll
            for (int j = 0; j < 4; ++j)
                g0[kvt * 4 + j] = Sm[kvt * 16 + quad * 4 + j][dt * 16 + la];
        #pragma unroll
        for (int kvt = 0; kvt < 2; ++kvt)
            #pragma unroll
            for (int j = 0; j < 4; ++j)
                g1[kvt * 4 + j] = Sm[(kvt + 2) * 16 + quad * 4 + j][dt * 16 + la];
        unsigned short* vt = xt + ((size_t)(bh * 32 + lt)) * 4096;
        *(u16x8*)(vt + (dt * 64 + lane) * 16)     = g0;
        *(u16x8*)(vt + (dt * 64 + lane) * 16 + 8) = g1;
    }
}

// ---------------------------------------------------------------------------
// Kernel 3: flash attention, transpose-free. grid (32 bh, 16 qt, 2 ks);
// block 256 = 4 waves, wave owns 32 q rows, each block does 16 KV tiles.
// S^T = K·Q^T (16x16x32); P stays in REGISTERS: its C-layout IS the B-frag
// layout of mfma_f32_16x16x16bf16_1k, so O^T = V^T·P^T directly. K and V both
// double-buffered in LDS (frag-major, flat global_load_lds). 1 barrier/iter.
// ---------------------------------------------------------------------------
__global__ __launch_bounds__(256) void attn_kernel(const unsigned short* __restrict__ xb,
                                                   const unsigned short* __restrict__ xt,
                                                   unsigned short* __restrict__ po,
                                                   float* __restrict__ pl) {
    const int bh = blockIdx.x;
    const int qt = blockIdx.y;
    const int ks = blockIdx.z;
    const int tid = threadIdx.x;
    const int w = tid >> 6, lane = tid & 63;
    const int la = lane & 15, quad = lane >> 4;

    __shared__ __align__(16) unsigned short KL[2][4096];
    __shared__ __align__(16) unsigned short VL[2][4096];

    const unsigned short* xbh = xb + (size_t)bh * 32 * 4096;
    const unsigned short* xth = xt + (size_t)bh * 32 * 4096;
    const int qbase = qt * 128 + w * 32;
    const int t0 = ks * 16;

    // Q B-frags from frag-major xb (global, once)
    bf16x8 qf[2][2];
    #pragma unroll
    for (int qnt = 0; qnt < 2; ++qnt) {
        const int q0 = qbase + qnt * 16;
        const unsigned short* qs = xbh + (q0 >> 6) * 4096 + (((q0 >> 4) & 3) * 2) * 512;
        qf[qnt][0] = *(const bf16x8*)(qs + lane * 8);
        qf[qnt][1] = *(const bf16x8*)(qs + 512 + lane * 8);
    }

    const f32x4 fzero = {0.f, 0.f, 0.f, 0.f};
    f32x4 acc[2][4];   // [qnt][dt] : O^T tile, reg r -> d = dt*16+quad*4+r, col la -> q
    #pragma unroll
    for (int i = 0; i < 2; ++i)
        #pragma unroll
        for (int j = 0; j < 4; ++j) acc[i][j] = fzero;
    float lp[2] = {0.f, 0.f};

    // prologue: stage tile t0 (K and V) into buffer 0
    #pragma unroll
    for (int j = 0; j < 2; ++j) {
        const int off = (j * 256 + tid) * 16;
        GLOAD_LDS((const char*)(xbh + t0 * 4096) + off, (char*)KL[0] + off);
        GLOAD_LDS((const char*)(xth + t0 * 4096) + off, (char*)VL[0] + off);
    }
    __syncthreads();

    for (int tt = 0; tt < 16; ++tt) {
        // stage K(t+1) early: drained by this iter's barrier, read next iter
        if (tt < 15) {
            const char* ksrc = (const char*)(xbh + (t0 + tt + 1) * 4096);
            char* kdst = (char*)KL[(tt + 1) & 1];
            #pragma unroll
            for (int j = 0; j < 2; ++j) {
                const int off = (j * 256 + tid) * 16;
                GLOAD_LDS(ksrc + off, kdst + off);
            }
        }

        // --- S^T = K Q^T : K A-frags from LDS (lane-contiguous b128) ---
        const unsigned short* kb = KL[tt & 1];
        f32x4 st[4][2];
        #pragma unroll
        for (int kvt = 0; kvt < 4; ++kvt) {
            bf16x8 kf0 = *(const bf16x8*)(kb + (kvt * 2 + 0) * 512 + lane * 8);
            bf16x8 kf1 = *(const bf16x8*)(kb + (kvt * 2 + 1) * 512 + lane * 8);
            #pragma unroll
            for (int qnt = 0; qnt < 2; ++qnt) {
                f32x4 s = fzero;
                s = __builtin_amdgcn_mfma_f32_16x16x32_bf16(kf0, qf[qnt][0], s, 0, 0, 0);
                s = __builtin_amdgcn_mfma_f32_16x16x32_bf16(kf1, qf[qnt][1], s, 0, 0, 0);
                st[kvt][qnt] = s;
            }
        }

        // --- exp2 + pack to bf16x4 B-frags IN REGISTERS (no LDS round-trip) ---
        bf16x4 pf[2][4];
        #pragma unroll
        for (int qnt = 0; qnt < 2; ++qnt) {
            float ls = 0.f;
            #pragma unroll
            for (int kvt = 0; kvt < 4; ++kvt) {
                float p0 = __builtin_amdgcn_exp2f(st[kvt][qnt][0]);
                float p1 = __builtin_amdgcn_exp2f(st[kvt][qnt][1]);
                float p2 = __builtin_amdgcn_exp2f(st[kvt][qnt][2]);
                float p3 = __builtin_amdgcn_exp2f(st[kvt][qnt][3]);
                ls += (p0 + p1) + (p2 + p3);
                uint32_t u0 = __float_as_uint(p0) + 0x8000u;
                uint32_t u1 = __float_as_uint(p1) + 0x8000u;
                uint32_t u2 = __float_as_uint(p2) + 0x8000u;
                uint32_t u3 = __float_as_uint(p3) + 0x8000u;
                union { uint2 u; bf16x4 v; } cv;
                cv.u = make_uint2(__builtin_amdgcn_perm(u1, u0, 0x07060302),
                                  __builtin_amdgcn_perm(u3, u2, 0x07060302));
                pf[qnt][kvt] = cv.v;
            }
            lp[qnt] += ls;
        }

        __syncthreads();   // drains K(t+1)/V(t) stages; V(t) now readable

        // stage V(t+1): drained by next iter's barrier
        if (tt < 15) {
            const char* vsrc = (const char*)(xth + (t0 + tt + 1) * 4096);
            char* vdst = (char*)VL[(tt + 1) & 1];
            #pragma unroll
            for (int j = 0; j < 2; ++j) {
                const int off = (j * 256 + tid) * 16;
                GLOAD_LDS(vsrc + off, vdst + off);
            }
        }

        // --- O^T += V^T P^T : A = V frag (LDS), B = pf (registers!) ---
        const unsigned short* vb = VL[tt & 1];
        #pragma unroll
        for (int dt = 0; dt < 4; ++dt) {
            const unsigned short* vrow = vb + (dt * 64 + lane) * 16;
            #pragma unroll
            for (int kvt = 0; kvt < 4; ++kvt) {
                bf16x4 vf = *(const bf16x4*)(vrow + kvt * 4);
                #pragma unroll
                for (int qnt = 0; qnt < 2; ++qnt)
                    acc[qnt][dt] = __builtin_amdgcn_mfma_f32_16x16x16bf16_1k(
                        vf, pf[qnt][kvt], acc[qnt][dt], 0, 0, 0);
            }
        }
    }

    // --- epilogue: O^T tile: lane(la,quad) holds q=qnt*16+la, d=dt*16+quad*4+r ---
    const size_t prow = (size_t)(ks * 32 + bh) * 2048 + qbase;
    unsigned short* pob = po + prow * 64;
    #pragma unroll
    for (int qnt = 0; qnt < 2; ++qnt) {
        unsigned short* orow = pob + (size_t)(qnt * 16 + la) * 64 + quad * 4;
        #pragma unroll
        for (int dt = 0; dt < 4; ++dt) {
            f32x4 a = acc[qnt][dt];
            *(ushort4*)(orow + dt * 16) =
                make_ushort4(f2bs(a[0]), f2bs(a[1]), f2bs(a[2]), f2bs(a[3]));
        }
    }
    // l[q=qnt*16+la]: this lane's lp covers its quad's kv rows; sum across quads
    #pragma unroll
    for (int qnt = 0; qnt < 2; ++qnt) {
        float l = lp[qnt];
        l += __shfl_xor(l, 16);
        l += __shfl_xor(l, 32);
        if (quad == 0) pl[prow + qnt * 16 + la] = l;
    }
}

// ---------------------------------------------------------------------------
// Kernel 4: combine 2 KV-splits: ctx = (O1+O2)/(l1+l2), bf16 out.
// ---------------------------------------------------------------------------
__global__ __launch_bounds__(256) void reduce_kernel(const unsigned short* __restrict__ po,
                                                     const float* __restrict__ pl,
                                                     unsigned short* __restrict__ ctx) {
    const int gid = blockIdx.x * 256 + threadIdx.x;
    const int rid = gid >> 4;
    const int d0  = (gid & 15) * 4;
    const float invl = 1.0f / (pl[rid] + pl[65536 + rid]);
    ushort4 a = *(const ushort4*)(po + (size_t)rid * 64 + d0);
    ushort4 c = *(const ushort4*)(po + (size_t)65536 * 64 + (size_t)rid * 64 + d0);
    const int bh = rid >> 11, q = rid & 2047;
    const int b = bh >> 4, h = bh & 15;
    unsigned short* dst = ctx + (((size_t)(b * 2048 + q) * 16 + h) * 64) + d0;
    *(ushort4*)dst = make_ushort4(
        f2bs((bf2f(a.x) + bf2f(c.x)) * invl),
        f2bs((bf2f(a.y) + bf2f(c.y)) * invl),
        f2bs((bf2f(a.z) + bf2f(c.z)) * invl),
        f2bs((bf2f(a.w) + bf2f(c.w)) * invl));
}

// ---------------------------------------------------------------------------
// Kernel 5: out = ctx @ W^T + b (gemm_bt, bf16 MFMA, fp32 out). 128m x 64n.
// ---------------------------------------------------------------------------
__global__ __launch_bounds__(256) void proj_kernel(const unsigned short* __restrict__ A,
                                                   const unsigned short* __restrict__ Bw,
                                                   const float* __restrict__ bias,
                                                   float* __restrict__ out) {
    const int n0 = blockIdx.x * 64;
    const int m0 = blockIdx.y * 128;
    const int tid = threadIdx.x;
    const int w = tid >> 6, lane = tid & 63;
    const int la = lane & 15, quad = lane >> 4;
    const int wm = (w >> 1) * 64, wn = (w & 1) * 32;
    const int K = HDIM;

    __shared__ __align__(16) unsigned short As[128 * 32];
    __shared__ __align__(16) unsigned short Bs[64 * 32];

    const f32x4 fzero = {0.f, 0.f, 0.f, 0.f};
    f32x4 acc[4][2];
    #pragma unroll
    for (int i = 0; i < 4; ++i)
        #pragma unroll
        for (int j = 0; j < 2; ++j) acc[i][j] = fzero;

    for (int k0 = 0; k0 < K; k0 += 32) {
        __syncthreads();
        #pragma unroll
        for (int j = 0; j < 2; ++j) {
            const int fc = j * 256 + tid;
            GLOAD_LDS(A + (size_t)(m0 + (fc >> 2)) * K + k0 + (fc & 3) * 8, (char*)As + fc * 16);
        }
        GLOAD_LDS(Bw + (size_t)(n0 + (tid >> 2)) * K + k0 + (tid & 3) * 8, (char*)Bs + tid * 16);
        __syncthreads();

        bf16x8 af[4], bfr[2];
        #pragma unroll
        for (int mt = 0; mt < 4; ++mt) af[mt]  = *(const bf16x8*)&As[(wm + mt * 16 + la) * 32 + quad * 8];
        #pragma unroll
        for (int nt = 0; nt < 2; ++nt) bfr[nt] = *(const bf16x8*)&Bs[(wn + nt * 16 + la) * 32 + quad * 8];
        #pragma unroll
        for (int mt = 0; mt < 4; ++mt)
            #pragma unroll
            for (int nt = 0; nt < 2; ++nt)
                acc[mt][nt] = __builtin_amdgcn_mfma_f32_16x16x32_bf16(af[mt], bfr[nt], acc[mt][nt], 0, 0, 0);
    }

    #pragma unroll
    for (int nt = 0; nt < 2; ++nt) {
        const int n = n0 + wn + nt * 16 + la;
        const float bv = bias[n];
        #pragma unroll
        for (int mt = 0; mt < 4; ++mt)
            #pragma unroll
            for (int r = 0; r < 4; ++r) {
                const int m = m0 + wm + mt * 16 + quad * 4 + r;
                out[(size_t)m * HDIM + n] = acc[mt][nt][r] + bv;
            }
    }
}

// ---------------------------------------------------------------------------
extern "C" void kernel_launch(void* const* d_in, const int* in_sizes, int n_in,
                              void* d_out, int out_size, void* d_ws, size_t ws_size,
                              hipStream_t stream) {
    const float* x    = (const float*)d_in[0];
    const float* W    = (const float*)d_in[1];
    const float* bias = (const float*)d_in[2];
    float* out = (float*)d_out;

    // ws (bytes): ctx 8M | xb 8M | xt 8M | Wb 2M | po 16M | pl 0.5M
    unsigned short* ctx = (unsigned short*)d_ws;
    unsigned short* xbp = (unsigned short*)((char*)d_ws + ( 8u << 20));
    unsigned short* xtp = (unsigned short*)((char*)d_ws + (16u << 20));
    unsigned short* Wb  = (unsigned short*)((char*)d_ws + (24u << 20));
    unsigned short* po  = (unsigned short*)((char*)d_ws + (26u << 20));
    float*          pl  = (float*)         ((char*)d_ws + (42u << 20));

    cvt_kernel<<<dim3(HDIM * HDIM / 1024), 256, 0, stream>>>(W, Wb, HDIM * HDIM);
    xcvt_kernel<<<dim3(32, 32), 256, 0, stream>>>(x, xbp, xtp);
    attn_kernel<<<dim3(32, 16, 2), 256, 0, stream>>>(xbp, xtp, po, pl);
    reduce_kernel<<<dim3(4096), 256, 0, stream>>>(po, pl, ctx);
    proj_kernel<<<dim3(16, 32), 256, 0, stream>>>(ctx, Wb, bias, out);
}